// Round 7
// baseline (556.661 us; speedup 1.0000x reference)
//
#include <hip/hip_runtime.h>
#include <stdint.h>

#define NC 5
#define IMAXP1 33
#define SEGS 165            // 5 * 33
#define SEGS_PAD 192        // 6 M-tiles of 32
#define MT 6
#define HW_ (512 * 512)
#define IGNORE_L 255
#define TILE (SEGS_PAD * 128)

#define CHUNK_PX 16384              // pixels per segsum block
#define STAGE_PX 256                // pixels staged per iteration (1 KB/row)
#define NSTAGE (CHUNK_PX / STAGE_PX)  // 64
#define ROW_STRIDE 1040             // 1024 + 16 pad: even bank coverage
#define BUFSZ (32 * ROW_STRIDE)     // 33280 B per buffer
#define WTILE (SEGS_PAD * 32)       // per-wave partial tile (192 x 32)

typedef __attribute__((ext_vector_type(8))) short short8v;
typedef __attribute__((ext_vector_type(16))) float f32x16;
typedef __attribute__((ext_vector_type(2))) unsigned short u16x2;
typedef __attribute__((ext_vector_type(2))) float float2v;
typedef __attribute__((ext_vector_type(2))) __bf16 bf16x2;

// ---------------- Pass 1: seg ids + counts ----------------
__global__ __launch_bounds__(256) void seg_count_kernel(
    const int* __restrict__ labels, const int* __restrict__ indexes,
    uint8_t* __restrict__ seg, unsigned* __restrict__ counts,
    int pix_per_block) {
  __shared__ unsigned hist[SEGS];
  for (int i = threadIdx.x; i < SEGS; i += blockDim.x) hist[i] = 0u;
  __syncthreads();

  const long long base = (long long)blockIdx.x * pix_per_block;
  const int b = (int)(base / HW_);
  const int nvec = pix_per_block / 4;
  const int4* lab4 = (const int4*)(labels + base);
  const int4* idx4 = (const int4*)(indexes + base);
  uchar4* seg4 = (uchar4*)(seg + base);

  for (int k = threadIdx.x; k < nvec; k += blockDim.x) {
    int4 l = lab4[k];
    int4 ix = idx4[k];
    int s0 = (l.x == IGNORE_L) ? 0 : l.x * IMAXP1 + ix.x;
    int s1 = (l.y == IGNORE_L) ? 0 : l.y * IMAXP1 + ix.y;
    int s2 = (l.z == IGNORE_L) ? 0 : l.z * IMAXP1 + ix.z;
    int s3 = (l.w == IGNORE_L) ? 0 : l.w * IMAXP1 + ix.w;
    uchar4 sv;
    sv.x = (unsigned char)s0; sv.y = (unsigned char)s1;
    sv.z = (unsigned char)s2; sv.w = (unsigned char)s3;
    seg4[k] = sv;
    atomicAdd(&hist[s0], 1u);
    atomicAdd(&hist[s1], 1u);
    atomicAdd(&hist[s2], 1u);
    atomicAdd(&hist[s3], 1u);
  }
  __syncthreads();
  for (int i = threadIdx.x; i < SEGS; i += blockDim.x)
    if (hist[i]) atomicAdd(&counts[b * SEGS + i], hist[i]);
}

// ---------------- Pass 2: segment sums via one-hot MFMA GEMM ----------------
// Block = (image, 32-channel group, 16K-pixel chunk). Per 256-px stage each
// wave reads its 8 channel rows with ONE coalesced 1-KB load each (long DRAM
// bursts), reg-stages into LDS (issue-early / write-late), and B-fragments
// come from ds_read_b128. Waves split the stage pixels 4 ways (64 px each).
__global__ __launch_bounds__(256, 2) void segsum_mfma_kernel(
    const float* __restrict__ feat, const uint8_t* __restrict__ seg,
    float* __restrict__ partials) {
  __shared__ __align__(16) char sbuf[2 * BUFSZ];

  const int bid = blockIdx.x;
  const int b = bid >> 6;           // image
  const int g = (bid >> 4) & 3;     // channel group (32 ch)
  const int chunk = bid & 15;       // pixel chunk
  const int P0 = chunk * CHUNK_PX;

  const int l = threadIdx.x & 63;
  const int w = threadIdx.x >> 6;
  const int lane31 = l & 31;
  const int hi = l >> 5;

  const unsigned lane2 = (unsigned)lane31 | ((unsigned)lane31 << 16);

  // staging: wave w owns rows [w*8, w*8+8); lane l fetches 16 B chunklet l
  const float* gbase =
      feat + ((size_t)(b * 128 + g * 32 + w * 8)) * HW_ + P0 + l * 4;
  char* lwbase = sbuf + (w * 8) * ROW_STRIDE + l * 16;
  // compute: lane reads its channel row (lane31)
  const char* lrbase = sbuf + lane31 * ROW_STRIDE;
  const uint8_t* segg = seg + (size_t)b * HW_ + P0 + w * 64 + hi * 8;

  f32x16 acc[MT];
  #pragma unroll
  for (int m = 0; m < MT; ++m) acc[m] = (f32x16)(0.f);

  #define KSTEP(f0, f1, sb)                                           \
    do {                                                              \
      unsigned svp[4];                                                \
      _Pragma("unroll") for (int j = 0; j < 4; ++j) {                 \
        unsigned lo8 = (unsigned)(((sb) >> (16 * j)) & 0xFFull);      \
        unsigned hi8 = (unsigned)(((sb) >> (16 * j + 8)) & 0xFFull);  \
        svp[j] = (lo8 | (hi8 << 16)) ^ lane2;                         \
      }                                                               \
      float fs[8] = {(f0).x, (f0).y, (f0).z, (f0).w,                  \
                     (f1).x, (f1).y, (f1).z, (f1).w};                 \
      union { unsigned u[4]; short8v v; } bhi, blo;                   \
      _Pragma("unroll") for (int j = 0; j < 4; ++j) {                 \
        float2v f2 = {fs[2 * j], fs[2 * j + 1]};                      \
        bf16x2 h2 = __builtin_convertvector(f2, bf16x2);              \
        unsigned hb = __builtin_bit_cast(unsigned, h2);               \
        bhi.u[j] = hb;                                                \
        float fh0 = __builtin_bit_cast(float, hb << 16);              \
        float fh1 = __builtin_bit_cast(float, hb & 0xFFFF0000u);      \
        float2v l2 = {f2.x - fh0, f2.y - fh1};                        \
        bf16x2 lo2 = __builtin_convertvector(l2, bf16x2);             \
        blo.u[j] = __builtin_bit_cast(unsigned, lo2);                 \
      }                                                               \
      _Pragma("unroll") for (int m = 0; m < MT; ++m) {                \
        unsigned m2 = (unsigned)(m * 32) | ((unsigned)(m * 32) << 16);\
        union { unsigned u[4]; short8v v; } a;                        \
        _Pragma("unroll") for (int j = 0; j < 4; ++j) {               \
          u16x2 y = __builtin_bit_cast(u16x2, svp[j] ^ m2);           \
          u16x2 nz = __builtin_elementwise_min(y, (u16x2)(unsigned short)1); \
          u16x2 msk = nz - (u16x2)(unsigned short)1;                  \
          u16x2 av = msk & (u16x2)(unsigned short)0x3F80;             \
          a.u[j] = __builtin_bit_cast(unsigned, av);                  \
        }                                                             \
        acc[m] = __builtin_amdgcn_mfma_f32_32x32x16_bf16(a.v, bhi.v,  \
                                                         acc[m], 0, 0, 0); \
        acc[m] = __builtin_amdgcn_mfma_f32_32x32x16_bf16(a.v, blo.v,  \
                                                         acc[m], 0, 0, 0); \
      }                                                               \
    } while (0)

  // prologue: stage 0
  {
    float4 st[8];
    #pragma unroll
    for (int j = 0; j < 8; ++j) st[j] = *(const float4*)(gbase + (size_t)j * HW_);
    #pragma unroll
    for (int j = 0; j < 8; ++j) *(float4*)(lwbase + j * ROW_STRIDE) = st[j];
  }
  __syncthreads();

  for (int s = 0; s < NSTAGE; ++s) {
    const int buf = s & 1;
    float4 nx[8];
    if (s + 1 < NSTAGE) {
      #pragma unroll
      for (int j = 0; j < 8; ++j)
        nx[j] = *(const float4*)(gbase + (size_t)j * HW_ + (s + 1) * STAGE_PX);
    }

    const char* lb = lrbase + buf * BUFSZ;
    const uint8_t* sgs = segg + s * STAGE_PX;
    #pragma unroll
    for (int t = 0; t < 4; ++t) {
      const int kb = w * 64 + t * 16;
      float4 v0 = *(const float4*)(lb + (kb + hi * 8) * 4);
      float4 v1 = *(const float4*)(lb + (kb + hi * 8) * 4 + 16);
      unsigned long long sb = *(const unsigned long long*)(sgs + t * 16);
      KSTEP(v0, v1, sb);
    }

    if (s + 1 < NSTAGE) {
      #pragma unroll
      for (int j = 0; j < 8; ++j)
        *(float4*)(lwbase + (buf ^ 1) * BUFSZ + j * ROW_STRIDE) = nx[j];
    }
    __syncthreads();
  }

  // epilogue: per-wave partial tile (192 segs x 32 ch), plain coalesced stores
  float* pb = partials + ((size_t)bid * 4 + w) * WTILE;
  #pragma unroll
  for (int m = 0; m < MT; ++m) {
    #pragma unroll
    for (int r = 0; r < 16; ++r) {
      int srow = m * 32 + (r & 3) + 8 * (r >> 2) + 4 * hi;
      pb[srow * 32 + lane31] = acc[m][r];
    }
  }
}

// ---------------- Pass 2b: reduce per-wave partials ----------------
// sums[b][s][ch] = sum over 16 chunks x 4 waves of group g = ch>>5
__global__ __launch_bounds__(256) void reduce_partials_kernel(
    const float* __restrict__ partials, float* __restrict__ sums) {
  const int o = blockIdx.x * 256 + threadIdx.x;   // [0, TILE)
  const int b = blockIdx.y;
  const int s = o >> 7, ch = o & 127, g = ch >> 5, n = ch & 31;
  const float* p = partials + (size_t)(b * 4 + g) * 64 * WTILE + s * 32 + n;
  float t = 0.f;
  #pragma unroll 4
  for (int u = 0; u < 64; ++u) t += p[(size_t)u * WTILE];
  sums[(size_t)b * TILE + o] = t;
}

// ---------------- Pass 3: per-(image,class) pairwise loss ----------------
__global__ __launch_bounds__(256) void pairloss_kernel(
    const float* __restrict__ sums, const unsigned* __restrict__ counts,
    float* __restrict__ loss_sum, unsigned* __restrict__ nvalid, int D) {
  const int b = blockIdx.x / NC;
  const int c = blockIdx.x % NC;

  __shared__ float sh_mean[32 * 128];
  __shared__ float sh_cnt[IMAXP1];
  __shared__ int list[IMAXP1];
  __shared__ int Ksh;
  __shared__ uchar2 pairs[32 * 31 / 2];
  __shared__ double wred[4];

  if (threadIdx.x == 0) {
    int K = 0;
    for (int i = 1; i < IMAXP1; ++i) {   // slot 0 (ignore key) excluded
      unsigned cnt = counts[b * SEGS + c * IMAXP1 + i];
      if (cnt >= 2u) {                   // singleton segments excluded
        list[K] = i;
        sh_cnt[K] = (float)cnt;
        ++K;
      }
    }
    Ksh = K;
    int p = 0;
    for (int i = 0; i < K; ++i)
      for (int j = i + 1; j < K; ++j) {
        pairs[p].x = (unsigned char)i;
        pairs[p].y = (unsigned char)j;
        ++p;
      }
  }
  __syncthreads();
  const int K = Ksh;
  if (K == 0) return;

  for (int idx = threadIdx.x; idx < K * D; idx += blockDim.x) {
    int k = idx / 128, d = idx % 128;    // D==128
    int s = c * IMAXP1 + list[k];
    sh_mean[k * 128 + d] =
        sums[(size_t)b * TILE + s * 128 + d] / sh_cnt[k];
  }
  __syncthreads();

  const int npairs = K * (K - 1) / 2;
  const int total = npairs * 128;
  float local = 0.f;
  for (int idx = threadIdx.x; idx < total; idx += blockDim.x) {
    int p = idx >> 7, d = idx & 127;
    int i = pairs[p].x, j = pairs[p].y;
    local += fabsf(sh_mean[i * 128 + d] - sh_mean[j * 128 + d]);
  }

  double v = (double)local;
  #pragma unroll
  for (int off = 32; off; off >>= 1) v += __shfl_down(v, off, 64);
  const int wave = threadIdx.x >> 6;
  if ((threadIdx.x & 63) == 0) wred[wave] = v;
  __syncthreads();
  if (threadIdx.x == 0) {
    double ssum = 2.0 * (wred[0] + wred[1] + wred[2] + wred[3]);
    double ret = ssum / ((double)K * (double)K * (double)D);
    double loss = (ret < 1.0) ? 0.5 * ret * ret : ret - 0.5;
    atomicAdd(loss_sum, (float)loss);
    atomicAdd(nvalid, 1u);
  }
}

// ---------------- Pass 4: finalize ----------------
__global__ void finalize_kernel(const float* __restrict__ loss_sum,
                                const unsigned* __restrict__ nvalid,
                                float* __restrict__ out, int B) {
  if (threadIdx.x == 0) {
    unsigned n = *nvalid;
    out[0] = n ? (*loss_sum / (float)n) / (float)B : 0.f;
  }
}

extern "C" void kernel_launch(void* const* d_in, const int* in_sizes, int n_in,
                              void* d_out, int out_size, void* d_ws,
                              size_t ws_size, hipStream_t stream) {
  const float* feat = (const float*)d_in[0];
  const int* labels = (const int*)d_in[1];
  const int* indexes = (const int*)d_in[2];

  const int npix_total = in_sizes[1];          // B*H*W
  const int B = npix_total / HW_;              // 8
  const int D = in_sizes[0] / npix_total;      // 128
  const int nblocks = B * 4 * (HW_ / CHUNK_PX);  // 8*4*16 = 512

  // ws: [seg bytes][partials f32 nblocks*4*WTILE][sums f32 B*TILE][counts][loss]
  uint8_t* seg = (uint8_t*)d_ws;
  size_t off = ((size_t)npix_total + 255) & ~(size_t)255;
  float* partials = (float*)((char*)d_ws + off);
  size_t part_bytes = (size_t)nblocks * 4 * WTILE * sizeof(float);
  float* sums = (float*)((char*)d_ws + off + part_bytes);
  size_t sums_bytes = (size_t)B * TILE * sizeof(float);
  unsigned* counts = (unsigned*)((char*)d_ws + off + part_bytes + sums_bytes);
  size_t counts_bytes = (size_t)B * SEGS * sizeof(unsigned);
  float* loss_sum =
      (float*)((char*)d_ws + off + part_bytes + sums_bytes + counts_bytes);
  unsigned* nvalid = (unsigned*)(loss_sum + 1);

  hipMemsetAsync(counts, 0, counts_bytes + 2 * sizeof(unsigned), stream);

  const int pix_per_block = 4096;
  seg_count_kernel<<<npix_total / pix_per_block, 256, 0, stream>>>(
      labels, indexes, seg, counts, pix_per_block);

  segsum_mfma_kernel<<<nblocks, 256, 0, stream>>>(feat, seg, partials);

  dim3 rgrid(TILE / 256, B);
  reduce_partials_kernel<<<rgrid, 256, 0, stream>>>(partials, sums);

  pairloss_kernel<<<B * NC, 256, 0, stream>>>(sums, counts, loss_sum, nvalid,
                                              D);
  finalize_kernel<<<1, 64, 0, stream>>>(loss_sum, nvalid, (float*)d_out, B);
}

// Round 8
// 448.327 us; speedup vs baseline: 1.2416x; 1.2416x over previous
//
#include <hip/hip_runtime.h>
#include <stdint.h>

#define NC 5
#define SEGS 160            // remapped: label*32 + (idx-1), idx in [1,32]
#define MT 5                // 5 M-tiles of 32
#define HW_ (512 * 512)
#define IGNORE_L 255
#define SENT 0xFF           // sentinel seg byte for ignored pixels
#define KCHUNK 2048         // pixels per segsum block
#define NSUP (KCHUNK / 32)  // 32-pixel supersteps (2 ksteps each)
#define TILE (SEGS * 128)

typedef __attribute__((ext_vector_type(8))) short short8v;
typedef __attribute__((ext_vector_type(16))) float f32x16;
typedef __attribute__((ext_vector_type(2))) unsigned short u16x2;
typedef __attribute__((ext_vector_type(2))) float float2v;
typedef __attribute__((ext_vector_type(2))) __bf16 bf16x2;
typedef __attribute__((ext_vector_type(2))) unsigned long long u64x2;

// ---------------- Pass 1: remapped seg ids + counts ----------------
__global__ __launch_bounds__(256) void seg_count_kernel(
    const int* __restrict__ labels, const int* __restrict__ indexes,
    uint8_t* __restrict__ seg, unsigned* __restrict__ counts,
    int pix_per_block) {
  __shared__ unsigned hist[SEGS + 1];     // slot 160 = ignore bucket
  for (int i = threadIdx.x; i < SEGS + 1; i += blockDim.x) hist[i] = 0u;
  __syncthreads();

  const long long base = (long long)blockIdx.x * pix_per_block;
  const int b = (int)(base / HW_);
  const int nvec = pix_per_block / 4;
  const int4* lab4 = (const int4*)(labels + base);
  const int4* idx4 = (const int4*)(indexes + base);
  uchar4* seg4 = (uchar4*)(seg + base);

  for (int k = threadIdx.x; k < nvec; k += blockDim.x) {
    int4 l = lab4[k];
    int4 ix = idx4[k];
    int s0 = (l.x == IGNORE_L) ? SEGS : l.x * 32 + ix.x - 1;
    int s1 = (l.y == IGNORE_L) ? SEGS : l.y * 32 + ix.y - 1;
    int s2 = (l.z == IGNORE_L) ? SEGS : l.z * 32 + ix.z - 1;
    int s3 = (l.w == IGNORE_L) ? SEGS : l.w * 32 + ix.w - 1;
    uchar4 sv;
    sv.x = (unsigned char)(s0 == SEGS ? SENT : s0);
    sv.y = (unsigned char)(s1 == SEGS ? SENT : s1);
    sv.z = (unsigned char)(s2 == SEGS ? SENT : s2);
    sv.w = (unsigned char)(s3 == SEGS ? SENT : s3);
    seg4[k] = sv;
    atomicAdd(&hist[s0], 1u);
    atomicAdd(&hist[s1], 1u);
    atomicAdd(&hist[s2], 1u);
    atomicAdd(&hist[s3], 1u);
  }
  __syncthreads();
  for (int i = threadIdx.x; i < SEGS; i += blockDim.x)
    if (hist[i]) atomicAdd(&counts[b * SEGS + i], hist[i]);
}

// ---------------- Pass 2: segment sums via one-hot MFMA GEMM ----------------
// sums[s,d] += sum_p onehot[s,p] * feat[p,d]; bf16 split-float (hi+lo) MFMA,
// f32 accumulation. 32-px supersteps, 3-deep register pipeline, NO barriers,
// seg bytes read from L2-resident map. MT=5 (160 remapped segs), acc=80 VGPR.
struct SS {
  float4 f[4];   // 16 px of this lane's channel
  u64x2 g;       // 16 seg bytes for those px
};

__global__ __launch_bounds__(256, 3) void segsum_mfma_kernel(
    const float* __restrict__ feat, const uint8_t* __restrict__ seg,
    float* __restrict__ sums, int chunks_per_img) {
  const int b = blockIdx.x / chunks_per_img;
  const int chunk = blockIdx.x % chunks_per_img;
  const int pbase = chunk * KCHUNK;

  const int l = threadIdx.x & 63;
  const int w = threadIdx.x >> 6;
  const int lane31 = l & 31;
  const int hi = l >> 5;
  const int ch = w * 32 + lane31;

  // lane's channel-row base (float4 units), + hi*16px share
  const float4* fp4 =
      (const float4*)(feat + ((size_t)b * 128 + ch) * HW_ + pbase) + hi * 4;
  const uint8_t* sp = seg + (size_t)b * HW_ + pbase + hi * 16;

  // per-tile packed one-hot targets: (m*32+lane31) in both u16 halves
  unsigned tgt2[MT];
  #pragma unroll
  for (int m = 0; m < MT; ++m) {
    unsigned t = (unsigned)(m * 32 + lane31);
    tgt2[m] = t | (t << 16);
  }

  f32x16 acc[MT];
  #pragma unroll
  for (int m = 0; m < MT; ++m) acc[m] = (f32x16)(0.f);

  #define LOAD_SS(dst, s)                                             \
    do {                                                              \
      _Pragma("unroll") for (int i = 0; i < 4; ++i)                   \
          (dst).f[i] = fp4[(size_t)(s)*8 + i];                        \
      (dst).g = *(const u64x2*)(sp + (size_t)(s)*32);                 \
    } while (0)

  #define KSTEP(f0, f1, sb)                                           \
    do {                                                              \
      unsigned svp[4];                                                \
      _Pragma("unroll") for (int j = 0; j < 4; ++j) {                 \
        unsigned lo8 = (unsigned)(((sb) >> (16 * j)) & 0xFFull);      \
        unsigned hi8 = (unsigned)(((sb) >> (16 * j + 8)) & 0xFFull);  \
        svp[j] = lo8 | (hi8 << 16);                                   \
      }                                                               \
      float fs[8] = {(f0).x, (f0).y, (f0).z, (f0).w,                  \
                     (f1).x, (f1).y, (f1).z, (f1).w};                 \
      union { unsigned u[4]; short8v v; } bhi, blo;                   \
      _Pragma("unroll") for (int j = 0; j < 4; ++j) {                 \
        float2v f2 = {fs[2 * j], fs[2 * j + 1]};                      \
        bf16x2 h2 = __builtin_convertvector(f2, bf16x2);              \
        unsigned hb = __builtin_bit_cast(unsigned, h2);               \
        bhi.u[j] = hb;                                                \
        float fh0 = __builtin_bit_cast(float, hb << 16);              \
        float fh1 = __builtin_bit_cast(float, hb & 0xFFFF0000u);      \
        float2v l2 = {f2.x - fh0, f2.y - fh1};                        \
        bf16x2 lo2 = __builtin_convertvector(l2, bf16x2);             \
        blo.u[j] = __builtin_bit_cast(unsigned, lo2);                 \
      }                                                               \
      _Pragma("unroll") for (int m = 0; m < MT; ++m) {                \
        union { unsigned u[4]; short8v v; } a;                        \
        _Pragma("unroll") for (int j = 0; j < 4; ++j) {               \
          u16x2 y = __builtin_bit_cast(u16x2, svp[j] ^ tgt2[m]);      \
          u16x2 nz = __builtin_elementwise_min(y, (u16x2)(unsigned short)1); \
          u16x2 msk = nz - (u16x2)(unsigned short)1;                  \
          u16x2 av = msk & (u16x2)(unsigned short)0x3F80;             \
          a.u[j] = __builtin_bit_cast(unsigned, av);                  \
        }                                                             \
        acc[m] = __builtin_amdgcn_mfma_f32_32x32x16_bf16(a.v, bhi.v,  \
                                                         acc[m], 0, 0, 0); \
        acc[m] = __builtin_amdgcn_mfma_f32_32x32x16_bf16(a.v, blo.v,  \
                                                         acc[m], 0, 0, 0); \
      }                                                               \
    } while (0)

  #define COMPUTE_SS(src)                                             \
    do {                                                              \
      KSTEP((src).f[0], (src).f[1], (src).g.x);                       \
      KSTEP((src).f[2], (src).f[3], (src).g.y);                       \
    } while (0)

  SS bA, bB, bC;
  LOAD_SS(bA, 0);
  LOAD_SS(bB, 1);
  for (int s = 0; s < NSUP; s += 3) {
    if (s + 2 < NSUP) LOAD_SS(bC, s + 2);
    COMPUTE_SS(bA);
    if (s + 3 < NSUP) LOAD_SS(bA, s + 3);
    if (s + 1 < NSUP) COMPUTE_SS(bB);
    if (s + 4 < NSUP) LOAD_SS(bB, s + 4);
    if (s + 2 < NSUP) COMPUTE_SS(bC);
  }

  // epilogue: C/D layout col=lane&31, row=(r&3)+8*(r>>2)+4*hi
  #pragma unroll
  for (int m = 0; m < MT; ++m) {
    #pragma unroll
    for (int r = 0; r < 16; ++r) {
      int s = m * 32 + (r & 3) + 8 * (r >> 2) + 4 * hi;
      float v = acc[m][r];
      if (v != 0.f)
        atomicAdd(&sums[((size_t)b * SEGS + s) * 128 + ch], v);
    }
  }
}

// ---------------- Pass 3: per-(image,class) pairwise loss ----------------
__global__ __launch_bounds__(256) void pairloss_kernel(
    const float* __restrict__ sums, const unsigned* __restrict__ counts,
    float* __restrict__ loss_sum, unsigned* __restrict__ nvalid, int D) {
  const int b = blockIdx.x / NC;
  const int c = blockIdx.x % NC;

  __shared__ float sh_mean[32 * 128];
  __shared__ float sh_cnt[33];
  __shared__ int list[33];
  __shared__ int Ksh;
  __shared__ uchar2 pairs[32 * 31 / 2];
  __shared__ double wred[4];

  if (threadIdx.x == 0) {
    int K = 0;
    for (int ii = 0; ii < 32; ++ii) {    // remapped instance slots
      unsigned cnt = counts[b * SEGS + c * 32 + ii];
      if (cnt >= 2u) {                   // singleton segments excluded
        list[K] = ii;
        sh_cnt[K] = (float)cnt;
        ++K;
      }
    }
    Ksh = K;
    int p = 0;
    for (int i = 0; i < K; ++i)
      for (int j = i + 1; j < K; ++j) {
        pairs[p].x = (unsigned char)i;
        pairs[p].y = (unsigned char)j;
        ++p;
      }
  }
  __syncthreads();
  const int K = Ksh;
  if (K == 0) return;

  for (int idx = threadIdx.x; idx < K * D; idx += blockDim.x) {
    int k = idx / 128, d = idx % 128;    // D==128
    int s = c * 32 + list[k];
    sh_mean[k * 128 + d] = sums[((size_t)b * SEGS + s) * D + d] / sh_cnt[k];
  }
  __syncthreads();

  const int npairs = K * (K - 1) / 2;
  const int total = npairs * 128;
  float local = 0.f;
  for (int idx = threadIdx.x; idx < total; idx += blockDim.x) {
    int p = idx >> 7, d = idx & 127;
    int i = pairs[p].x, j = pairs[p].y;
    local += fabsf(sh_mean[i * 128 + d] - sh_mean[j * 128 + d]);
  }

  double v = (double)local;
  #pragma unroll
  for (int off = 32; off; off >>= 1) v += __shfl_down(v, off, 64);
  const int wave = threadIdx.x >> 6;
  if ((threadIdx.x & 63) == 0) wred[wave] = v;
  __syncthreads();
  if (threadIdx.x == 0) {
    double ssum = 2.0 * (wred[0] + wred[1] + wred[2] + wred[3]);
    double ret = ssum / ((double)K * (double)K * (double)D);
    double loss = (ret < 1.0) ? 0.5 * ret * ret : ret - 0.5;
    atomicAdd(loss_sum, (float)loss);
    atomicAdd(nvalid, 1u);
  }
}

// ---------------- Pass 4: finalize ----------------
__global__ void finalize_kernel(const float* __restrict__ loss_sum,
                                const unsigned* __restrict__ nvalid,
                                float* __restrict__ out, int B) {
  if (threadIdx.x == 0) {
    unsigned n = *nvalid;
    out[0] = n ? (*loss_sum / (float)n) / (float)B : 0.f;
  }
}

extern "C" void kernel_launch(void* const* d_in, const int* in_sizes, int n_in,
                              void* d_out, int out_size, void* d_ws,
                              size_t ws_size, hipStream_t stream) {
  const float* feat = (const float*)d_in[0];
  const int* labels = (const int*)d_in[1];
  const int* indexes = (const int*)d_in[2];

  const int npix_total = in_sizes[1];          // B*H*W
  const int B = npix_total / HW_;              // 8
  const int D = in_sizes[0] / npix_total;      // 128
  const int cpi = HW_ / KCHUNK;                // 128 chunks per image

  // ws: [seg bytes][sums f32 B*TILE][counts u32 B*SEGS][loss f32][n u32]
  uint8_t* seg = (uint8_t*)d_ws;
  size_t off = ((size_t)npix_total + 255) & ~(size_t)255;
  float* sums = (float*)((char*)d_ws + off);
  size_t sums_bytes = (size_t)B * TILE * sizeof(float);
  unsigned* counts = (unsigned*)((char*)d_ws + off + sums_bytes);
  size_t counts_bytes = (size_t)B * SEGS * sizeof(unsigned);
  float* loss_sum = (float*)((char*)d_ws + off + sums_bytes + counts_bytes);
  unsigned* nvalid = (unsigned*)(loss_sum + 1);

  hipMemsetAsync(sums, 0, sums_bytes + counts_bytes + 2 * sizeof(unsigned),
                 stream);

  const int pix_per_block = 4096;
  seg_count_kernel<<<npix_total / pix_per_block, 256, 0, stream>>>(
      labels, indexes, seg, counts, pix_per_block);

  segsum_mfma_kernel<<<B * cpi, 256, 0, stream>>>(feat, seg, sums, cpi);

  pairloss_kernel<<<B * NC, 256, 0, stream>>>(sums, counts, loss_sum, nvalid,
                                              D);
  finalize_kernel<<<1, 64, 0, stream>>>(loss_sum, nvalid, (float*)d_out, B);
}

// Round 9
// 318.252 us; speedup vs baseline: 1.7491x; 1.4087x over previous
//
#include <hip/hip_runtime.h>
#include <stdint.h>

#define NC 5
#define SEGS 160            // remapped: label*32 + (idx-1), idx in [1,32]
#define MT 5                // 5 M-tiles of 32
#define HW_ (512 * 512)
#define IGNORE_L 255
#define SENT 0xFF           // sentinel seg byte for ignored pixels
#define KCHUNK 2048         // pixels per segsum block
#define SUP_PX 128          // superstep pixels (lane reads 256 B contiguous)
#define NSUP (KCHUNK / SUP_PX)  // 16
#define TILE (SEGS * 128)

typedef __attribute__((ext_vector_type(8))) short short8v;
typedef __attribute__((ext_vector_type(16))) float f32x16;
typedef __attribute__((ext_vector_type(2))) unsigned short u16x2;
typedef __attribute__((ext_vector_type(2))) float float2v;
typedef __attribute__((ext_vector_type(2))) __bf16 bf16x2;
typedef __attribute__((ext_vector_type(2))) unsigned long long u64x2;

// ---------------- Pass 1: remapped seg ids + counts ----------------
__global__ __launch_bounds__(256) void seg_count_kernel(
    const int* __restrict__ labels, const int* __restrict__ indexes,
    uint8_t* __restrict__ seg, unsigned* __restrict__ counts,
    int pix_per_block) {
  __shared__ unsigned hist[SEGS + 1];     // slot 160 = ignore bucket
  for (int i = threadIdx.x; i < SEGS + 1; i += blockDim.x) hist[i] = 0u;
  __syncthreads();

  const long long base = (long long)blockIdx.x * pix_per_block;
  const int b = (int)(base / HW_);
  const int nvec = pix_per_block / 4;
  const int4* lab4 = (const int4*)(labels + base);
  const int4* idx4 = (const int4*)(indexes + base);
  uchar4* seg4 = (uchar4*)(seg + base);

  for (int k = threadIdx.x; k < nvec; k += blockDim.x) {
    int4 l = lab4[k];
    int4 ix = idx4[k];
    int s0 = (l.x == IGNORE_L) ? SEGS : l.x * 32 + ix.x - 1;
    int s1 = (l.y == IGNORE_L) ? SEGS : l.y * 32 + ix.y - 1;
    int s2 = (l.z == IGNORE_L) ? SEGS : l.z * 32 + ix.z - 1;
    int s3 = (l.w == IGNORE_L) ? SEGS : l.w * 32 + ix.w - 1;
    uchar4 sv;
    sv.x = (unsigned char)(s0 == SEGS ? SENT : s0);
    sv.y = (unsigned char)(s1 == SEGS ? SENT : s1);
    sv.z = (unsigned char)(s2 == SEGS ? SENT : s2);
    sv.w = (unsigned char)(s3 == SEGS ? SENT : s3);
    seg4[k] = sv;
    atomicAdd(&hist[s0], 1u);
    atomicAdd(&hist[s1], 1u);
    atomicAdd(&hist[s2], 1u);
    atomicAdd(&hist[s3], 1u);
  }
  __syncthreads();
  for (int i = threadIdx.x; i < SEGS; i += blockDim.x)
    if (hist[i]) atomicAdd(&counts[b * SEGS + i], hist[i]);
}

// ---------------- Pass 2: segment sums via one-hot MFMA GEMM ----------------
// sums[s,d] += sum_p onehot[s,p] * feat[p,d]; bf16 split-float (hi+lo) MFMA,
// f32 accumulation. Superstep = 128 px: each lane reads 256 B CONTIGUOUS
// (16x float4) of its channel row before the 1 MB jump (DRAM row locality).
// 2-deep register pipeline, seg bytes LDS-staged once per block.
struct SS {
  float4 f[16];   // 64 px of this lane's channel (256 B contiguous)
};

__global__ __launch_bounds__(256, 2) void segsum_mfma_kernel(
    const float* __restrict__ feat, const uint8_t* __restrict__ seg,
    float* __restrict__ sums, int chunks_per_img) {
  __shared__ unsigned long long sseg8[KCHUNK / 8];
  const int b = blockIdx.x / chunks_per_img;
  const int chunk = blockIdx.x % chunks_per_img;
  const int pbase = chunk * KCHUNK;

  const unsigned long long* gseg8 =
      (const unsigned long long*)(seg + (size_t)b * HW_ + pbase);
  sseg8[threadIdx.x] = gseg8[threadIdx.x];
  __syncthreads();

  const int l = threadIdx.x & 63;
  const int w = threadIdx.x >> 6;
  const int lane31 = l & 31;
  const int hi = l >> 5;
  const int ch = w * 32 + lane31;

  // lane's channel-row base; hi-half owns px [s*128+hi*64, +64)
  const float4* fp4 =
      (const float4*)(feat + ((size_t)b * 128 + ch) * HW_ + pbase) + hi * 16;
  const uint8_t* sp = (const uint8_t*)sseg8 + hi * 64;

  // per-tile packed one-hot targets: (m*32+lane31) in both u16 halves
  unsigned tgt2[MT];
  #pragma unroll
  for (int m = 0; m < MT; ++m) {
    unsigned t = (unsigned)(m * 32 + lane31);
    tgt2[m] = t | (t << 16);
  }

  f32x16 acc[MT];
  #pragma unroll
  for (int m = 0; m < MT; ++m) acc[m] = (f32x16)(0.f);

  #define LOAD_SS(dst, s)                                             \
    do {                                                              \
      _Pragma("unroll") for (int i = 0; i < 16; ++i)                  \
          (dst).f[i] = fp4[(size_t)(s)*32 + i];                       \
    } while (0)

  #define KSTEP(f0, f1, sb)                                           \
    do {                                                              \
      unsigned svp[4];                                                \
      _Pragma("unroll") for (int j = 0; j < 4; ++j) {                 \
        unsigned lo8 = (unsigned)(((sb) >> (16 * j)) & 0xFFull);      \
        unsigned hi8 = (unsigned)(((sb) >> (16 * j + 8)) & 0xFFull);  \
        svp[j] = lo8 | (hi8 << 16);                                   \
      }                                                               \
      float fs[8] = {(f0).x, (f0).y, (f0).z, (f0).w,                  \
                     (f1).x, (f1).y, (f1).z, (f1).w};                 \
      union { unsigned u[4]; short8v v; } bhi, blo;                   \
      _Pragma("unroll") for (int j = 0; j < 4; ++j) {                 \
        float2v f2 = {fs[2 * j], fs[2 * j + 1]};                      \
        bf16x2 h2 = __builtin_convertvector(f2, bf16x2);              \
        unsigned hb = __builtin_bit_cast(unsigned, h2);               \
        bhi.u[j] = hb;                                                \
        float fh0 = __builtin_bit_cast(float, hb << 16);              \
        float fh1 = __builtin_bit_cast(float, hb & 0xFFFF0000u);      \
        float2v l2 = {f2.x - fh0, f2.y - fh1};                        \
        bf16x2 lo2 = __builtin_convertvector(l2, bf16x2);             \
        blo.u[j] = __builtin_bit_cast(unsigned, lo2);                 \
      }                                                               \
      _Pragma("unroll") for (int m = 0; m < MT; ++m) {                \
        union { unsigned u[4]; short8v v; } a;                        \
        _Pragma("unroll") for (int j = 0; j < 4; ++j) {               \
          u16x2 y = __builtin_bit_cast(u16x2, svp[j] ^ tgt2[m]);      \
          u16x2 nz = __builtin_elementwise_min(y, (u16x2)(unsigned short)1); \
          u16x2 msk = nz - (u16x2)(unsigned short)1;                  \
          u16x2 av = msk & (u16x2)(unsigned short)0x3F80;             \
          a.u[j] = __builtin_bit_cast(unsigned, av);                  \
        }                                                             \
        acc[m] = __builtin_amdgcn_mfma_f32_32x32x16_bf16(a.v, bhi.v,  \
                                                         acc[m], 0, 0, 0); \
        acc[m] = __builtin_amdgcn_mfma_f32_32x32x16_bf16(a.v, blo.v,  \
                                                         acc[m], 0, 0, 0); \
      }                                                               \
    } while (0)

  // 8 ksteps per superstep; seg bytes read from LDS (fast, not pipelined)
  #define COMPUTE_SS(src, s)                                          \
    do {                                                              \
      u64x2 g0 = *(const u64x2*)(sp + (size_t)(s)*128);               \
      u64x2 g1 = *(const u64x2*)(sp + (size_t)(s)*128 + 16);          \
      u64x2 g2 = *(const u64x2*)(sp + (size_t)(s)*128 + 32);          \
      u64x2 g3 = *(const u64x2*)(sp + (size_t)(s)*128 + 48);          \
      KSTEP((src).f[0], (src).f[1], g0.x);                            \
      KSTEP((src).f[2], (src).f[3], g0.y);                            \
      KSTEP((src).f[4], (src).f[5], g1.x);                            \
      KSTEP((src).f[6], (src).f[7], g1.y);                            \
      KSTEP((src).f[8], (src).f[9], g2.x);                            \
      KSTEP((src).f[10], (src).f[11], g2.y);                          \
      KSTEP((src).f[12], (src).f[13], g3.x);                          \
      KSTEP((src).f[14], (src).f[15], g3.y);                          \
    } while (0)

  SS bufA, bufB;
  LOAD_SS(bufA, 0);
  for (int s = 0; s < NSUP; s += 2) {
    LOAD_SS(bufB, s + 1);
    COMPUTE_SS(bufA, s);
    if (s + 2 < NSUP) LOAD_SS(bufA, s + 2);
    COMPUTE_SS(bufB, s + 1);
  }

  // epilogue: C/D layout col=lane&31, row=(r&3)+8*(r>>2)+4*hi
  #pragma unroll
  for (int m = 0; m < MT; ++m) {
    #pragma unroll
    for (int r = 0; r < 16; ++r) {
      int s = m * 32 + (r & 3) + 8 * (r >> 2) + 4 * hi;
      float v = acc[m][r];
      if (v != 0.f)
        atomicAdd(&sums[((size_t)b * SEGS + s) * 128 + ch], v);
    }
  }
}

// ---------------- Pass 3: per-(image,class) pairwise loss ----------------
__global__ __launch_bounds__(256) void pairloss_kernel(
    const float* __restrict__ sums, const unsigned* __restrict__ counts,
    float* __restrict__ loss_sum, unsigned* __restrict__ nvalid, int D) {
  const int b = blockIdx.x / NC;
  const int c = blockIdx.x % NC;

  __shared__ float sh_mean[32 * 128];
  __shared__ float sh_cnt[33];
  __shared__ int list[33];
  __shared__ int Ksh;
  __shared__ uchar2 pairs[32 * 31 / 2];
  __shared__ double wred[4];

  if (threadIdx.x == 0) {
    int K = 0;
    for (int ii = 0; ii < 32; ++ii) {    // remapped instance slots
      unsigned cnt = counts[b * SEGS + c * 32 + ii];
      if (cnt >= 2u) {                   // singleton segments excluded
        list[K] = ii;
        sh_cnt[K] = (float)cnt;
        ++K;
      }
    }
    Ksh = K;
    int p = 0;
    for (int i = 0; i < K; ++i)
      for (int j = i + 1; j < K; ++j) {
        pairs[p].x = (unsigned char)i;
        pairs[p].y = (unsigned char)j;
        ++p;
      }
  }
  __syncthreads();
  const int K = Ksh;
  if (K == 0) return;

  for (int idx = threadIdx.x; idx < K * D; idx += blockDim.x) {
    int k = idx / 128, d = idx % 128;    // D==128
    int s = c * 32 + list[k];
    sh_mean[k * 128 + d] = sums[((size_t)b * SEGS + s) * D + d] / sh_cnt[k];
  }
  __syncthreads();

  const int npairs = K * (K - 1) / 2;
  const int total = npairs * 128;
  float local = 0.f;
  for (int idx = threadIdx.x; idx < total; idx += blockDim.x) {
    int p = idx >> 7, d = idx & 127;
    int i = pairs[p].x, j = pairs[p].y;
    local += fabsf(sh_mean[i * 128 + d] - sh_mean[j * 128 + d]);
  }

  double v = (double)local;
  #pragma unroll
  for (int off = 32; off; off >>= 1) v += __shfl_down(v, off, 64);
  const int wave = threadIdx.x >> 6;
  if ((threadIdx.x & 63) == 0) wred[wave] = v;
  __syncthreads();
  if (threadIdx.x == 0) {
    double ssum = 2.0 * (wred[0] + wred[1] + wred[2] + wred[3]);
    double ret = ssum / ((double)K * (double)K * (double)D);
    double loss = (ret < 1.0) ? 0.5 * ret * ret : ret - 0.5;
    atomicAdd(loss_sum, (float)loss);
    atomicAdd(nvalid, 1u);
  }
}

// ---------------- Pass 4: finalize ----------------
__global__ void finalize_kernel(const float* __restrict__ loss_sum,
                                const unsigned* __restrict__ nvalid,
                                float* __restrict__ out, int B) {
  if (threadIdx.x == 0) {
    unsigned n = *nvalid;
    out[0] = n ? (*loss_sum / (float)n) / (float)B : 0.f;
  }
}

extern "C" void kernel_launch(void* const* d_in, const int* in_sizes, int n_in,
                              void* d_out, int out_size, void* d_ws,
                              size_t ws_size, hipStream_t stream) {
  const float* feat = (const float*)d_in[0];
  const int* labels = (const int*)d_in[1];
  const int* indexes = (const int*)d_in[2];

  const int npix_total = in_sizes[1];          // B*H*W
  const int B = npix_total / HW_;              // 8
  const int D = in_sizes[0] / npix_total;      // 128
  const int cpi = HW_ / KCHUNK;                // 128 chunks per image

  // ws: [seg bytes][sums f32 B*TILE][counts u32 B*SEGS][loss f32][n u32]
  uint8_t* seg = (uint8_t*)d_ws;
  size_t off = ((size_t)npix_total + 255) & ~(size_t)255;
  float* sums = (float*)((char*)d_ws + off);
  size_t sums_bytes = (size_t)B * TILE * sizeof(float);
  unsigned* counts = (unsigned*)((char*)d_ws + off + sums_bytes);
  size_t counts_bytes = (size_t)B * SEGS * sizeof(unsigned);
  float* loss_sum = (float*)((char*)d_ws + off + sums_bytes + counts_bytes);
  unsigned* nvalid = (unsigned*)(loss_sum + 1);

  hipMemsetAsync(sums, 0, sums_bytes + counts_bytes + 2 * sizeof(unsigned),
                 stream);

  const int pix_per_block = 4096;
  seg_count_kernel<<<npix_total / pix_per_block, 256, 0, stream>>>(
      labels, indexes, seg, counts, pix_per_block);

  segsum_mfma_kernel<<<B * cpi, 256, 0, stream>>>(feat, seg, sums, cpi);

  pairloss_kernel<<<B * NC, 256, 0, stream>>>(sums, counts, loss_sum, nvalid,
                                              D);
  finalize_kernel<<<1, 64, 0, stream>>>(loss_sum, nvalid, (float*)d_out, B);
}